// Round 1
// 257.835 us; speedup vs baseline: 1.0205x; 1.0205x over previous
//
#include <hip/hip_runtime.h>

#define Bn 4096
#define En 1024
#define On 16
#define Hn 1024
#define OHn (On * Hn)

#define BM 64
#define BN 128
#define BK 64

using floatx4 = __attribute__((ext_vector_type(4))) float;
using float4v = __attribute__((ext_vector_type(4))) float;
using bf16x8  = __attribute__((ext_vector_type(8))) __bf16;
using short8v = __attribute__((ext_vector_type(8))) short;
using short4v = __attribute__((ext_vector_type(4))) short;

__device__ inline unsigned short f2bf(float f) {
    unsigned u = __builtin_bit_cast(unsigned, f);
    u += 0x7fffu + ((u >> 16) & 1u);   // RNE to bf16 (inputs finite)
    return (unsigned short)(u >> 16);
}

// ---------------- bucket examples by op ----------------
__global__ void bucket_kernel(const int* __restrict__ op_idx,
                              int* __restrict__ sorted_idx,
                              int* __restrict__ offsets) {
    __shared__ int cnt[On], cur[On], off[On + 1];
    int tid = threadIdx.x;
    if (tid < On) { cnt[tid] = 0; cur[tid] = 0; }
    __syncthreads();
    for (int i = tid; i < Bn; i += blockDim.x) atomicAdd(&cnt[op_idx[i]], 1);
    __syncthreads();
    if (tid == 0) {
        int s = 0;
        for (int o = 0; o < On; ++o) { off[o] = s; s += cnt[o]; }
        off[On] = s;
    }
    __syncthreads();
    for (int i = tid; i < Bn; i += blockDim.x) {
        int o = op_idx[i];
        int p = off[o] + atomicAdd(&cur[o], 1);
        sorted_idx[p] = i;
    }
    if (tid <= On) offsets[tid] = off[tid];
}

// ---------------- pack x: gather rows into sorted order, fp32 -> bf16 ----------------
// grid: Bn blocks x 256 thr. Each block = one sorted row (4 KB read, 2 KB write).
__global__ __launch_bounds__(256) void pack_x_kernel(const float* __restrict__ x,
                                                     const int* __restrict__ sorted_idx,
                                                     unsigned short* __restrict__ x_s) {
    int p = blockIdx.x;
    int row = sorted_idx[p];
    int t = threadIdx.x;
    float4v v = *(const float4v*)(x + (size_t)row * En + t * 4);
    short4v w;
#pragma unroll
    for (int j = 0; j < 4; ++j) w[j] = (short)f2bf(v[j]);
    *(short4v*)&x_s[(size_t)p * En + t * 4] = w;
}

// ---------------- pack W: [K][O][H] fp32 -> [O][K/8][H][8] bf16 (MFMA granule layout) ----
// Streaming transpose: 8192 blocks (32k waves) fully hide the 64KB-strided reads.
// grid: (Hn/256, K/8, On) x 256 thr. Works for W1 (K=En) and W2 (K=Hn); both 1024.
__global__ __launch_bounds__(256) void pack_w_kernel(const float* __restrict__ W,
                                                     unsigned short* __restrict__ Wp) {
    int o = blockIdx.z;
    int g = blockIdx.y;
    int h = blockIdx.x * 256 + threadIdx.x;
    const float* src = W + (size_t)(g * 8) * OHn + (size_t)o * Hn + h;
    short8v v;
#pragma unroll
    for (int j = 0; j < 8; ++j) v[j] = (short)f2bf(src[(size_t)j * OHn]);
    *(short8v*)&Wp[(((size_t)o * 128 + g) * Hn + h) * 8] = v;  // 16B cell, wave writes 1KB contig
}

// ---------------- layer 1: h1 = relu(x_s @ W1p[o] + b1[o]) ----------------
// All staging loads are contiguous 16B short8v (coalesced 1KB/wave); in-reg double buffer.
__global__ __launch_bounds__(256) void gemm1_kernel(
    const unsigned short* __restrict__ x_s, const unsigned short* __restrict__ Wp,
    const float* __restrict__ bias1, const int* __restrict__ offsets,
    unsigned short* __restrict__ h1) {
    int o = blockIdx.z;
    int off = offsets[o];
    int cnt = offsets[o + 1] - off;
    int m0 = blockIdx.y * BM;
    if (m0 >= cnt) return;
    int n0 = blockIdx.x * BN;

    __shared__ unsigned short As[8][BM][8];
    __shared__ unsigned short Bs[8][BN][8];

    int tid = threadIdx.x;

    // A staging: thread owns cells (g=ag, row=arow) and (g=ag+4, row=arow)
    int arow = tid & 63;
    int ag = tid >> 6;
    int rr0 = m0 + arow; if (rr0 >= cnt) rr0 = cnt - 1;   // clamp: garbage row only affects unwritten output rows
    const unsigned short* aptr = x_s + (size_t)(off + rr0) * En;

    // B staging: thread owns n=bn, granules bg, bg+2, bg+4, bg+6
    int bn = tid & 127;
    int bg = tid >> 7;   // 0 or 1
    const unsigned short* bptr = Wp + (((size_t)o * 128 + bg) * Hn + n0 + bn) * 8;

    short8v a_pre[2], b_pre[4];
    floatx4 acc[2][4] = {};
    int lane = tid & 63;
    int wave = tid >> 6;
    int wm = (wave >> 1) * 32;
    int wn = (wave & 1) * 64;
    int l15 = lane & 15;
    int kg = lane >> 4;

    // prologue: tile 0 -> regs
#pragma unroll
    for (int i = 0; i < 2; ++i) a_pre[i] = *(const short8v*)(aptr + (ag + 4 * i) * 8);
#pragma unroll
    for (int i = 0; i < 4; ++i) b_pre[i] = *(const short8v*)(bptr + (size_t)i * (2 * Hn * 8));

    for (int kt = 0; kt < En; kt += BK) {
        // regs -> LDS (b128, conflict-free)
#pragma unroll
        for (int i = 0; i < 2; ++i) *(short8v*)&As[ag + 4 * i][arow][0] = a_pre[i];
#pragma unroll
        for (int i = 0; i < 4; ++i) *(short8v*)&Bs[bg + 2 * i][bn][0] = b_pre[i];
        __syncthreads();

        // prefetch next tile into regs (overlaps MFMA)
        int ktn = kt + BK;
        if (ktn < En) {
#pragma unroll
            for (int i = 0; i < 2; ++i) a_pre[i] = *(const short8v*)(aptr + ktn + (ag + 4 * i) * 8);
#pragma unroll
            for (int i = 0; i < 4; ++i)
                b_pre[i] = *(const short8v*)(bptr + (size_t)ktn * Hn + (size_t)i * (2 * Hn * 8));
        }

        // compute: 2 k-steps of K=32
#pragma unroll
        for (int ks = 0; ks < 2; ++ks) {
            int g = ks * 4 + kg;
            bf16x8 af[2], bfr[4];
#pragma unroll
            for (int mt = 0; mt < 2; ++mt) af[mt] = *(const bf16x8*)&As[g][wm + mt * 16 + l15][0];
#pragma unroll
            for (int nt = 0; nt < 4; ++nt) bfr[nt] = *(const bf16x8*)&Bs[g][wn + nt * 16 + l15][0];
#pragma unroll
            for (int mt = 0; mt < 2; ++mt)
#pragma unroll
                for (int nt = 0; nt < 4; ++nt)
                    acc[mt][nt] = __builtin_amdgcn_mfma_f32_16x16x32_bf16(af[mt], bfr[nt], acc[mt][nt], 0, 0, 0);
        }
        __syncthreads();
    }

    // epilogue: bias + relu -> h1 (bf16, sorted order)
    int r4 = (lane >> 4) * 4;
#pragma unroll
    for (int nt = 0; nt < 4; ++nt) {
        int col = n0 + wn + nt * 16 + l15;
        float bv = bias1[o * Hn + col];
#pragma unroll
        for (int mt = 0; mt < 2; ++mt) {
#pragma unroll
            for (int r = 0; r < 4; ++r) {
                int row = m0 + wm + mt * 16 + r4 + r;
                if (row < cnt) {
                    float v = acc[mt][nt][r] + bv;
                    v = v > 0.f ? v : 0.f;
                    h1[(size_t)(off + row) * Hn + col] = f2bf(v);
                }
            }
        }
    }
}

// ---------------- layer 2: out[sel] = relu(h1 @ W2p[o] + b2[o]) ----------------
__global__ __launch_bounds__(256) void gemm2_kernel(
    const unsigned short* __restrict__ h1, const unsigned short* __restrict__ Wp,
    const float* __restrict__ bias2, const int* __restrict__ sorted_idx,
    const int* __restrict__ offsets, float* __restrict__ out) {
    int o = blockIdx.z;
    int off = offsets[o];
    int cnt = offsets[o + 1] - off;
    int m0 = blockIdx.y * BM;
    if (m0 >= cnt) return;
    int n0 = blockIdx.x * BN;

    __shared__ unsigned short As[8][BM][8];
    __shared__ unsigned short Bs[8][BN][8];

    int tid = threadIdx.x;

    int arow = tid & 63;
    int ag = tid >> 6;
    int rr0 = m0 + arow; if (rr0 >= cnt) rr0 = cnt - 1;
    const unsigned short* aptr = h1 + (size_t)(off + rr0) * Hn;

    int bn = tid & 127;
    int bg = tid >> 7;
    const unsigned short* bptr = Wp + (((size_t)o * 128 + bg) * Hn + n0 + bn) * 8;

    short8v a_pre[2], b_pre[4];
    floatx4 acc[2][4] = {};
    int lane = tid & 63;
    int wave = tid >> 6;
    int wm = (wave >> 1) * 32;
    int wn = (wave & 1) * 64;
    int l15 = lane & 15;
    int kg = lane >> 4;

#pragma unroll
    for (int i = 0; i < 2; ++i) a_pre[i] = *(const short8v*)(aptr + (ag + 4 * i) * 8);
#pragma unroll
    for (int i = 0; i < 4; ++i) b_pre[i] = *(const short8v*)(bptr + (size_t)i * (2 * Hn * 8));

    for (int kt = 0; kt < Hn; kt += BK) {
#pragma unroll
        for (int i = 0; i < 2; ++i) *(short8v*)&As[ag + 4 * i][arow][0] = a_pre[i];
#pragma unroll
        for (int i = 0; i < 4; ++i) *(short8v*)&Bs[bg + 2 * i][bn][0] = b_pre[i];
        __syncthreads();

        int ktn = kt + BK;
        if (ktn < Hn) {
#pragma unroll
            for (int i = 0; i < 2; ++i) a_pre[i] = *(const short8v*)(aptr + ktn + (ag + 4 * i) * 8);
#pragma unroll
            for (int i = 0; i < 4; ++i)
                b_pre[i] = *(const short8v*)(bptr + (size_t)ktn * Hn + (size_t)i * (2 * Hn * 8));
        }

#pragma unroll
        for (int ks = 0; ks < 2; ++ks) {
            int g = ks * 4 + kg;
            bf16x8 af[2], bfr[4];
#pragma unroll
            for (int mt = 0; mt < 2; ++mt) af[mt] = *(const bf16x8*)&As[g][wm + mt * 16 + l15][0];
#pragma unroll
            for (int nt = 0; nt < 4; ++nt) bfr[nt] = *(const bf16x8*)&Bs[g][wn + nt * 16 + l15][0];
#pragma unroll
            for (int mt = 0; mt < 2; ++mt)
#pragma unroll
                for (int nt = 0; nt < 4; ++nt)
                    acc[mt][nt] = __builtin_amdgcn_mfma_f32_16x16x32_bf16(af[mt], bfr[nt], acc[mt][nt], 0, 0, 0);
        }
        __syncthreads();
    }

    // epilogue: bias + relu, scatter rows back to original order (fp32)
    int r4 = (lane >> 4) * 4;
    float bv[4];
#pragma unroll
    for (int nt = 0; nt < 4; ++nt) bv[nt] = bias2[o * Hn + n0 + wn + nt * 16 + l15];
#pragma unroll
    for (int mt = 0; mt < 2; ++mt) {
#pragma unroll
        for (int r = 0; r < 4; ++r) {
            int row = m0 + wm + mt * 16 + r4 + r;
            if (row < cnt) {
                int b = sorted_idx[off + row];
                float* orow = out + (size_t)b * Hn + n0 + wn + l15;
#pragma unroll
                for (int nt = 0; nt < 4; ++nt) {
                    float v = acc[mt][nt][r] + bv[nt];
                    orow[nt * 16] = v > 0.f ? v : 0.f;
                }
            }
        }
    }
}

// ================= fallback (previous verified path, used only if ws too small) =================
__global__ __launch_bounds__(256) void gemm1_direct(
    const float* __restrict__ x, const float* __restrict__ W1,
    const float* __restrict__ bias1, const int* __restrict__ sorted_idx,
    const int* __restrict__ offsets, unsigned short* __restrict__ h1) {
    int o = blockIdx.z;
    int off = offsets[o];
    int cnt = offsets[o + 1] - off;
    int m0 = blockIdx.y * BM;
    if (m0 >= cnt) return;
    int n0 = blockIdx.x * BN;

    __shared__ unsigned short As[8][BM][8];
    __shared__ unsigned short Bs[8][BN][8];

    int tid = threadIdx.x;
    int arow = tid & 63;
    int ag = tid >> 6;
    const float* aptr = nullptr;
    if (m0 + arow < cnt) aptr = x + (size_t)sorted_idx[off + m0 + arow] * En;

    int bn = tid & 127;
    int bg0 = (tid >> 7) * 4;
    const float* bptr = W1 + (size_t)o * Hn + n0 + bn;

    float a_pre[16] = {};
    float b_pre[32];

    floatx4 acc[2][4] = {};
    int lane = tid & 63;
    int wave = tid >> 6;
    int wm = (wave >> 1) * 32;
    int wn = (wave & 1) * 64;
    int l15 = lane & 15;
    int kg = lane >> 4;

#pragma unroll
    for (int i = 0; i < 2; ++i) {
        int k = (ag + 4 * i) * 8;
        if (aptr) {
            *(float4v*)&a_pre[i * 8]     = *(const float4v*)(aptr + k);
            *(float4v*)&a_pre[i * 8 + 4] = *(const float4v*)(aptr + k + 4);
        }
    }
#pragma unroll
    for (int g = 0; g < 4; ++g)
#pragma unroll
        for (int j = 0; j < 8; ++j)
            b_pre[g * 8 + j] = bptr[(size_t)((bg0 + g) * 8 + j) * OHn];

    for (int kt = 0; kt < En; kt += BK) {
#pragma unroll
        for (int i = 0; i < 2; ++i) {
            short8v v;
#pragma unroll
            for (int j = 0; j < 8; ++j) v[j] = (short)f2bf(a_pre[i * 8 + j]);
            *(short8v*)&As[ag + 4 * i][arow][0] = v;
        }
#pragma unroll
        for (int g = 0; g < 4; ++g) {
            short8v v;
#pragma unroll
            for (int j = 0; j < 8; ++j) v[j] = (short)f2bf(b_pre[g * 8 + j]);
            *(short8v*)&Bs[bg0 + g][bn][0] = v;
        }
        __syncthreads();

        int ktn = kt + BK;
        if (ktn < En) {
#pragma unroll
            for (int i = 0; i < 2; ++i) {
                int k = ktn + (ag + 4 * i) * 8;
                if (aptr) {
                    *(float4v*)&a_pre[i * 8]     = *(const float4v*)(aptr + k);
                    *(float4v*)&a_pre[i * 8 + 4] = *(const float4v*)(aptr + k + 4);
                }
            }
#pragma unroll
            for (int g = 0; g < 4; ++g)
#pragma unroll
                for (int j = 0; j < 8; ++j)
                    b_pre[g * 8 + j] = bptr[(size_t)(ktn + (bg0 + g) * 8 + j) * OHn];
        }

#pragma unroll
        for (int ks = 0; ks < 2; ++ks) {
            int g = ks * 4 + kg;
            bf16x8 af[2], bfr[4];
#pragma unroll
            for (int mt = 0; mt < 2; ++mt) af[mt] = *(const bf16x8*)&As[g][wm + mt * 16 + l15][0];
#pragma unroll
            for (int nt = 0; nt < 4; ++nt) bfr[nt] = *(const bf16x8*)&Bs[g][wn + nt * 16 + l15][0];
#pragma unroll
            for (int mt = 0; mt < 2; ++mt)
#pragma unroll
                for (int nt = 0; nt < 4; ++nt)
                    acc[mt][nt] = __builtin_amdgcn_mfma_f32_16x16x32_bf16(af[mt], bfr[nt], acc[mt][nt], 0, 0, 0);
        }
        __syncthreads();
    }

    int r4 = (lane >> 4) * 4;
#pragma unroll
    for (int nt = 0; nt < 4; ++nt) {
        int col = n0 + wn + nt * 16 + l15;
        float bv = bias1[o * Hn + col];
#pragma unroll
        for (int mt = 0; mt < 2; ++mt) {
#pragma unroll
            for (int r = 0; r < 4; ++r) {
                int row = m0 + wm + mt * 16 + r4 + r;
                if (row < cnt) {
                    float v = acc[mt][nt][r] + bv;
                    v = v > 0.f ? v : 0.f;
                    h1[(size_t)(off + row) * Hn + col] = f2bf(v);
                }
            }
        }
    }
}

__global__ __launch_bounds__(256) void gemm2_direct(
    const unsigned short* __restrict__ h1, const float* __restrict__ W2,
    const float* __restrict__ bias2, const int* __restrict__ sorted_idx,
    const int* __restrict__ offsets, float* __restrict__ out) {
    int o = blockIdx.z;
    int off = offsets[o];
    int cnt = offsets[o + 1] - off;
    int m0 = blockIdx.y * BM;
    if (m0 >= cnt) return;
    int n0 = blockIdx.x * BN;

    __shared__ unsigned short As[8][BM][8];
    __shared__ unsigned short Bs[8][BN][8];

    int tid = threadIdx.x;
    int arow = tid & 63;
    int ag = tid >> 6;
    const unsigned short* aptr = nullptr;
    if (m0 + arow < cnt) aptr = h1 + (size_t)(off + m0 + arow) * Hn;

    int bn = tid & 127;
    int bg0 = (tid >> 7) * 4;
    const float* bptr = W2 + (size_t)o * Hn + n0 + bn;

    short8v a_pre[2] = {};
    float b_pre[32];

    floatx4 acc[2][4] = {};
    int lane = tid & 63;
    int wave = tid >> 6;
    int wm = (wave >> 1) * 32;
    int wn = (wave & 1) * 64;
    int l15 = lane & 15;
    int kg = lane >> 4;

#pragma unroll
    for (int i = 0; i < 2; ++i)
        if (aptr) a_pre[i] = *(const short8v*)(aptr + (ag + 4 * i) * 8);
#pragma unroll
    for (int g = 0; g < 4; ++g)
#pragma unroll
        for (int j = 0; j < 8; ++j)
            b_pre[g * 8 + j] = bptr[(size_t)((bg0 + g) * 8 + j) * OHn];

    for (int kt = 0; kt < Hn; kt += BK) {
#pragma unroll
        for (int i = 0; i < 2; ++i)
            *(short8v*)&As[ag + 4 * i][arow][0] = a_pre[i];
#pragma unroll
        for (int g = 0; g < 4; ++g) {
            short8v v;
#pragma unroll
            for (int j = 0; j < 8; ++j) v[j] = (short)f2bf(b_pre[g * 8 + j]);
            *(short8v*)&Bs[bg0 + g][bn][0] = v;
        }
        __syncthreads();

        int ktn = kt + BK;
        if (ktn < Hn) {
#pragma unroll
            for (int i = 0; i < 2; ++i)
                if (aptr) a_pre[i] = *(const short8v*)(aptr + ktn + (ag + 4 * i) * 8);
#pragma unroll
            for (int g = 0; g < 4; ++g)
#pragma unroll
                for (int j = 0; j < 8; ++j)
                    b_pre[g * 8 + j] = bptr[(size_t)(ktn + (bg0 + g) * 8 + j) * OHn];
        }

#pragma unroll
        for (int ks = 0; ks < 2; ++ks) {
            int g = ks * 4 + kg;
            bf16x8 af[2], bfr[4];
#pragma unroll
            for (int mt = 0; mt < 2; ++mt) af[mt] = *(const bf16x8*)&As[g][wm + mt * 16 + l15][0];
#pragma unroll
            for (int nt = 0; nt < 4; ++nt) bfr[nt] = *(const bf16x8*)&Bs[g][wn + nt * 16 + l15][0];
#pragma unroll
            for (int mt = 0; mt < 2; ++mt)
#pragma unroll
                for (int nt = 0; nt < 4; ++nt)
                    acc[mt][nt] = __builtin_amdgcn_mfma_f32_16x16x32_bf16(af[mt], bfr[nt], acc[mt][nt], 0, 0, 0);
        }
        __syncthreads();
    }

    int r4 = (lane >> 4) * 4;
    float bv[4];
#pragma unroll
    for (int nt = 0; nt < 4; ++nt) bv[nt] = bias2[o * Hn + n0 + wn + nt * 16 + l15];
#pragma unroll
    for (int mt = 0; mt < 2; ++mt) {
#pragma unroll
        for (int r = 0; r < 4; ++r) {
            int row = m0 + wm + mt * 16 + r4 + r;
            if (row < cnt) {
                int b = sorted_idx[off + row];
                float* orow = out + (size_t)b * Hn + n0 + wn + l15;
#pragma unroll
                for (int nt = 0; nt < 4; ++nt) {
                    float v = acc[mt][nt][r] + bv[nt];
                    orow[nt * 16] = v > 0.f ? v : 0.f;
                }
            }
        }
    }
}

extern "C" void kernel_launch(void* const* d_in, const int* in_sizes, int n_in,
                              void* d_out, int out_size, void* d_ws, size_t ws_size,
                              hipStream_t stream) {
    const float* x      = (const float*)d_in[0];
    const int*   op_idx = (const int*)d_in[1];
    const float* W1     = (const float*)d_in[2];
    const float* bias1  = (const float*)d_in[3];
    const float* W2     = (const float*)d_in[4];
    const float* bias2  = (const float*)d_in[5];
    float* out = (float*)d_out;

    char* ws = (char*)d_ws;
    int* offsets    = (int*)ws;                 // 17 ints
    int* sorted_idx = (int*)(ws + 256);         // 4096 ints

    // new-path workspace: x_s (8MB) | h1 (8MB) | Wp (32MB, reused for W1 then W2)
    const size_t X_S_BYTES = (size_t)Bn * En * 2;
    const size_t H1_BYTES  = (size_t)Bn * Hn * 2;
    const size_t WP_BYTES  = (size_t)On * 128 * Hn * 8 * 2;
    const size_t need = 16640 + X_S_BYTES + H1_BYTES + WP_BYTES;

    hipLaunchKernelGGL(bucket_kernel, dim3(1), dim3(1024), 0, stream,
                       op_idx, sorted_idx, offsets);

    if (ws_size >= need) {
        unsigned short* x_s = (unsigned short*)(ws + 16640);
        unsigned short* h1  = x_s + (size_t)Bn * En;
        unsigned short* Wp  = h1 + (size_t)Bn * Hn;

        dim3 grid(Hn / BN, Bn / BM, On);
        hipLaunchKernelGGL(pack_x_kernel, dim3(Bn), dim3(256), 0, stream,
                           x, sorted_idx, x_s);
        hipLaunchKernelGGL(pack_w_kernel, dim3(Hn / 256, En / 8, On), dim3(256), 0, stream,
                           W1, Wp);
        hipLaunchKernelGGL(gemm1_kernel, grid, dim3(256), 0, stream,
                           x_s, Wp, bias1, offsets, h1);
        hipLaunchKernelGGL(pack_w_kernel, dim3(Hn / 256, Hn / 8, On), dim3(256), 0, stream,
                           W2, Wp);
        hipLaunchKernelGGL(gemm2_kernel, grid, dim3(256), 0, stream,
                           h1, Wp, bias2, sorted_idx, offsets, out);
    } else {
        unsigned short* h1 = (unsigned short*)(ws + 256 + 16384);
        dim3 grid(Hn / BN, Bn / BM, On);
        hipLaunchKernelGGL(gemm1_direct, grid, dim3(256), 0, stream,
                           x, W1, bias1, sorted_idx, offsets, h1);
        hipLaunchKernelGGL(gemm2_direct, grid, dim3(256), 0, stream,
                           h1, W2, bias2, sorted_idx, offsets, out);
    }
}

// Round 2
// 241.529 us; speedup vs baseline: 1.0894x; 1.0675x over previous
//
#include <hip/hip_runtime.h>

#define Bn 4096
#define En 1024
#define On 16
#define Hn 1024
#define OHn (On * Hn)

#define BM 64
#define BN 128
#define BK 64
#define MAXT 80   // max tiles: sum ceil(cnt/64) <= 64 + 16

using floatx4 = __attribute__((ext_vector_type(4))) float;
using float4v = __attribute__((ext_vector_type(4))) float;
using bf16x8  = __attribute__((ext_vector_type(8))) __bf16;
using short8v = __attribute__((ext_vector_type(8))) short;
using short4v = __attribute__((ext_vector_type(4))) short;

__device__ inline unsigned short f2bf(float f) {
    unsigned u = __builtin_bit_cast(unsigned, f);
    u += 0x7fffu + ((u >> 16) & 1u);   // RNE to bf16 (inputs finite)
    return (unsigned short)(u >> 16);
}

// async global -> LDS, 16 bytes per lane (wave-uniform LDS base + lane*16)
__device__ __forceinline__ void gld16(const unsigned short* g, unsigned short* l) {
    __builtin_amdgcn_global_load_lds(
        (const __attribute__((address_space(1))) unsigned int*)g,
        (__attribute__((address_space(3))) unsigned int*)l, 16, 0, 0);
}

// ---------------- bucket examples by op + build compact tile list ----------------
__global__ void bucket_kernel(const int* __restrict__ op_idx,
                              int* __restrict__ sorted_idx,
                              int* __restrict__ offsets,
                              int* __restrict__ tile_o,
                              int* __restrict__ tile_m) {
    __shared__ int cnt[On], cur[On], off[On + 1];
    int tid = threadIdx.x;
    if (tid < On) { cnt[tid] = 0; cur[tid] = 0; }
    __syncthreads();
    for (int i = tid; i < Bn; i += blockDim.x) atomicAdd(&cnt[op_idx[i]], 1);
    __syncthreads();
    if (tid == 0) {
        int s = 0;
        for (int o = 0; o < On; ++o) { off[o] = s; s += cnt[o]; }
        off[On] = s;
        int nt = 0;
        for (int o = 0; o < On; ++o)
            for (int m0 = 0; m0 < cnt[o]; m0 += BM) { tile_o[nt] = o; tile_m[nt] = m0; ++nt; }
        for (; nt < MAXT; ++nt) { tile_o[nt] = -1; tile_m[nt] = 0; }
    }
    __syncthreads();
    for (int i = tid; i < Bn; i += blockDim.x) {
        int o = op_idx[i];
        int p = off[o] + atomicAdd(&cur[o], 1);
        sorted_idx[p] = i;
    }
    if (tid <= On) offsets[tid] = off[tid];
}

// ---------------- pack helpers ----------------
// W [K][O][H] fp32 -> Wp [O][K/8][H][8] bf16 (MFMA granule layout)
__device__ __forceinline__ void pack_w_block(const float* __restrict__ W,
                                             unsigned short* __restrict__ Wp,
                                             int o, int g, int hblk, int t) {
    int h = hblk * 256 + t;
    const float* src = W + (size_t)(g * 8) * OHn + (size_t)o * Hn + h;
    short8v v;
#pragma unroll
    for (int j = 0; j < 8; ++j) v[j] = (short)f2bf(src[(size_t)j * OHn]);
    *(short8v*)&Wp[(((size_t)o * 128 + g) * Hn + h) * 8] = v;
}

__device__ __forceinline__ void pack_x_block(const float* __restrict__ x,
                                             const int* __restrict__ sorted_idx,
                                             unsigned short* __restrict__ x_s,
                                             int p, int t) {
    int row = sorted_idx[p];
    float4v v = *(const float4v*)(x + (size_t)row * En + t * 4);
    short4v w;
#pragma unroll
    for (int j = 0; j < 4; ++j) w[j] = (short)f2bf(v[j]);
    *(short4v*)&x_s[(size_t)p * En + t * 4] = w;
}

// one kernel: pack W1 (blocks 0..8191), W2 (8192..16383), gather+cvt x (16384..20479)
__global__ __launch_bounds__(256) void pack_all_kernel(
    const float* __restrict__ W1, const float* __restrict__ W2,
    const float* __restrict__ x, const int* __restrict__ sorted_idx,
    unsigned short* __restrict__ Wp1, unsigned short* __restrict__ Wp2,
    unsigned short* __restrict__ x_s) {
    int b = blockIdx.x, t = threadIdx.x;
    if (b < 8192) {
        pack_w_block(W1, Wp1, b >> 9, (b >> 2) & 127, b & 3, t);
    } else if (b < 16384) {
        int c = b - 8192;
        pack_w_block(W2, Wp2, c >> 9, (c >> 2) & 127, c & 3, t);
    } else {
        pack_x_block(x, sorted_idx, x_s, b - 16384, t);
    }
}

// fallback-tier standalone packs (used only if ws can't hold both Wp buffers)
__global__ __launch_bounds__(256) void pack_x_kernel(const float* __restrict__ x,
                                                     const int* __restrict__ sorted_idx,
                                                     unsigned short* __restrict__ x_s) {
    pack_x_block(x, sorted_idx, x_s, blockIdx.x, threadIdx.x);
}
__global__ __launch_bounds__(256) void pack_w_kernel(const float* __restrict__ W,
                                                     unsigned short* __restrict__ Wp) {
    pack_w_block(W, Wp, blockIdx.z, blockIdx.y, blockIdx.x, threadIdx.x);
}

// ---------------- layer 1: h1 = relu(x_s @ W1p[o] + b1[o]) ----------------
// global_load_lds staging + LDS double buffer; one barrier per K-step.
__global__ __launch_bounds__(256) void gemm1_kernel(
    const unsigned short* __restrict__ x_s, const unsigned short* __restrict__ Wp,
    const float* __restrict__ bias1, const int* __restrict__ offsets,
    const int* __restrict__ tile_o, const int* __restrict__ tile_m,
    unsigned short* __restrict__ h1) {
    int o = tile_o[blockIdx.y];
    if (o < 0) return;
    int m0 = tile_m[blockIdx.y];
    int off = offsets[o];
    int cnt = offsets[o + 1] - off;
    int n0 = blockIdx.x * BN;

    __shared__ __attribute__((aligned(16))) unsigned short As[2][8][BM][8];  // 16 KB
    __shared__ __attribute__((aligned(16))) unsigned short Bs[2][8][BN][8];  // 32 KB

    int tid = threadIdx.x;

    // A staging: thread owns granule cells (ag, arow) and (ag+4, arow); lane-linear 16B cells
    int arow = tid & 63, ag = tid >> 6;
    int rr = m0 + arow; if (rr >= cnt) rr = cnt - 1;   // clamp: pad rows never stored
    const unsigned short* aBase = x_s + (size_t)(off + rr) * En;

    // B staging: thread owns n=bn, granules bg, bg+2, bg+4, bg+6; lane-linear 16B cells
    int bn = tid & 127, bg = tid >> 7;
    const unsigned short* bBase = Wp + (((size_t)o * 128 + bg) * Hn + n0 + bn) * 8;

    auto STAGE = [&](int buf, int kt) {
        gld16(aBase + kt + ag * 8,        &As[buf][ag][arow][0]);
        gld16(aBase + kt + (ag + 4) * 8,  &As[buf][ag + 4][arow][0]);
        const unsigned short* bk = bBase + (size_t)kt * Hn;   // (kt/8)*Hn*8
#pragma unroll
        for (int i = 0; i < 4; ++i)
            gld16(bk + (size_t)i * (2 * Hn * 8), &Bs[buf][bg + 2 * i][bn][0]);
    };

    floatx4 acc[2][4] = {};
    int lane = tid & 63, wave = tid >> 6;
    int wm = (wave >> 1) * 32, wn = (wave & 1) * 64;
    int l15 = lane & 15, kg = lane >> 4;

    auto COMPUTE = [&](int buf) {
#pragma unroll
        for (int ks = 0; ks < 2; ++ks) {
            int g = ks * 4 + kg;
            bf16x8 af[2], bfr[4];
#pragma unroll
            for (int mt = 0; mt < 2; ++mt) af[mt] = *(const bf16x8*)&As[buf][g][wm + mt * 16 + l15][0];
#pragma unroll
            for (int nt = 0; nt < 4; ++nt) bfr[nt] = *(const bf16x8*)&Bs[buf][g][wn + nt * 16 + l15][0];
#pragma unroll
            for (int mt = 0; mt < 2; ++mt)
#pragma unroll
                for (int nt = 0; nt < 4; ++nt)
                    acc[mt][nt] = __builtin_amdgcn_mfma_f32_16x16x32_bf16(af[mt], bfr[nt], acc[mt][nt], 0, 0, 0);
        }
    };

    STAGE(0, 0);
    for (int kt = 0; kt < En; kt += 2 * BK) {
        __syncthreads();                 // drains vmcnt: buf0 ready; buf1 free
        STAGE(1, kt + BK);               // async prefetch overlaps MFMA below
        COMPUTE(0);
        __syncthreads();                 // buf1 ready; buf0 free
        if (kt + 2 * BK < En) STAGE(0, kt + 2 * BK);
        COMPUTE(1);
    }

    // epilogue: bias + relu -> h1 (bf16, sorted order)
    int r4 = (lane >> 4) * 4;
#pragma unroll
    for (int nt = 0; nt < 4; ++nt) {
        int col = n0 + wn + nt * 16 + l15;
        float bv = bias1[o * Hn + col];
#pragma unroll
        for (int mt = 0; mt < 2; ++mt) {
#pragma unroll
            for (int r = 0; r < 4; ++r) {
                int row = m0 + wm + mt * 16 + r4 + r;
                if (row < cnt) {
                    float v = acc[mt][nt][r] + bv;
                    v = v > 0.f ? v : 0.f;
                    h1[(size_t)(off + row) * Hn + col] = f2bf(v);
                }
            }
        }
    }
}

// ---------------- layer 2: out[sel] = relu(h1 @ W2p[o] + b2[o]) ----------------
__global__ __launch_bounds__(256) void gemm2_kernel(
    const unsigned short* __restrict__ h1, const unsigned short* __restrict__ Wp,
    const float* __restrict__ bias2, const int* __restrict__ sorted_idx,
    const int* __restrict__ offsets, const int* __restrict__ tile_o,
    const int* __restrict__ tile_m, float* __restrict__ out) {
    int o = tile_o[blockIdx.y];
    if (o < 0) return;
    int m0 = tile_m[blockIdx.y];
    int off = offsets[o];
    int cnt = offsets[o + 1] - off;
    int n0 = blockIdx.x * BN;

    __shared__ __attribute__((aligned(16))) unsigned short As[2][8][BM][8];
    __shared__ __attribute__((aligned(16))) unsigned short Bs[2][8][BN][8];

    int tid = threadIdx.x;

    int arow = tid & 63, ag = tid >> 6;
    int rr = m0 + arow; if (rr >= cnt) rr = cnt - 1;
    const unsigned short* aBase = h1 + (size_t)(off + rr) * Hn;

    int bn = tid & 127, bg = tid >> 7;
    const unsigned short* bBase = Wp + (((size_t)o * 128 + bg) * Hn + n0 + bn) * 8;

    auto STAGE = [&](int buf, int kt) {
        gld16(aBase + kt + ag * 8,        &As[buf][ag][arow][0]);
        gld16(aBase + kt + (ag + 4) * 8,  &As[buf][ag + 4][arow][0]);
        const unsigned short* bk = bBase + (size_t)kt * Hn;
#pragma unroll
        for (int i = 0; i < 4; ++i)
            gld16(bk + (size_t)i * (2 * Hn * 8), &Bs[buf][bg + 2 * i][bn][0]);
    };

    floatx4 acc[2][4] = {};
    int lane = tid & 63, wave = tid >> 6;
    int wm = (wave >> 1) * 32, wn = (wave & 1) * 64;
    int l15 = lane & 15, kg = lane >> 4;

    auto COMPUTE = [&](int buf) {
#pragma unroll
        for (int ks = 0; ks < 2; ++ks) {
            int g = ks * 4 + kg;
            bf16x8 af[2], bfr[4];
#pragma unroll
            for (int mt = 0; mt < 2; ++mt) af[mt] = *(const bf16x8*)&As[buf][g][wm + mt * 16 + l15][0];
#pragma unroll
            for (int nt = 0; nt < 4; ++nt) bfr[nt] = *(const bf16x8*)&Bs[buf][g][wn + nt * 16 + l15][0];
#pragma unroll
            for (int mt = 0; mt < 2; ++mt)
#pragma unroll
                for (int nt = 0; nt < 4; ++nt)
                    acc[mt][nt] = __builtin_amdgcn_mfma_f32_16x16x32_bf16(af[mt], bfr[nt], acc[mt][nt], 0, 0, 0);
        }
    };

    STAGE(0, 0);
    for (int kt = 0; kt < Hn; kt += 2 * BK) {
        __syncthreads();
        STAGE(1, kt + BK);
        COMPUTE(0);
        __syncthreads();
        if (kt + 2 * BK < Hn) STAGE(0, kt + 2 * BK);
        COMPUTE(1);
    }

    // epilogue: bias + relu, scatter rows back to original order (fp32)
    int r4 = (lane >> 4) * 4;
    float bv[4];
#pragma unroll
    for (int nt = 0; nt < 4; ++nt) bv[nt] = bias2[o * Hn + n0 + wn + nt * 16 + l15];
#pragma unroll
    for (int mt = 0; mt < 2; ++mt) {
#pragma unroll
        for (int r = 0; r < 4; ++r) {
            int row = m0 + wm + mt * 16 + r4 + r;
            if (row < cnt) {
                int b = sorted_idx[off + row];
                float* orow = out + (size_t)b * Hn + n0 + wn + l15;
#pragma unroll
                for (int nt = 0; nt < 4; ++nt) {
                    float v = acc[mt][nt][r] + bv[nt];
                    orow[nt * 16] = v > 0.f ? v : 0.f;
                }
            }
        }
    }
}

extern "C" void kernel_launch(void* const* d_in, const int* in_sizes, int n_in,
                              void* d_out, int out_size, void* d_ws, size_t ws_size,
                              hipStream_t stream) {
    const float* x      = (const float*)d_in[0];
    const int*   op_idx = (const int*)d_in[1];
    const float* W1     = (const float*)d_in[2];
    const float* bias1  = (const float*)d_in[3];
    const float* W2     = (const float*)d_in[4];
    const float* bias2  = (const float*)d_in[5];
    float* out = (float*)d_out;

    char* ws = (char*)d_ws;
    int* offsets    = (int*)ws;                  // 17 ints
    int* sorted_idx = (int*)(ws + 256);          // 4096 ints
    int* tile_o     = (int*)(ws + 16640);        // MAXT ints
    int* tile_m     = (int*)(ws + 17152);        // MAXT ints

    const size_t HDR       = 32768;
    const size_t X_S_ELEMS = (size_t)Bn * En;            // bf16
    const size_t H1_ELEMS  = (size_t)Bn * Hn;            // bf16
    const size_t WP_ELEMS  = (size_t)On * 128 * Hn * 8;  // bf16, 32 MB
    const size_t need_full = HDR + 2 * (X_S_ELEMS + H1_ELEMS + WP_ELEMS);  // ~84 MB (x_s+h1+2*Wp)
    const size_t need_half = HDR + 2 * (X_S_ELEMS + H1_ELEMS + WP_ELEMS) - 2 * WP_ELEMS; // ~50 MB

    unsigned short* x_s = (unsigned short*)(ws + HDR);
    unsigned short* h1  = x_s + X_S_ELEMS;
    unsigned short* Wp1 = h1 + H1_ELEMS;
    unsigned short* Wp2 = Wp1 + WP_ELEMS;

    hipLaunchKernelGGL(bucket_kernel, dim3(1), dim3(1024), 0, stream,
                       op_idx, sorted_idx, offsets, tile_o, tile_m);

    dim3 grid_g(Hn / BN, MAXT);
    if (ws_size >= need_full) {
        hipLaunchKernelGGL(pack_all_kernel, dim3(20480), dim3(256), 0, stream,
                           W1, W2, x, sorted_idx, Wp1, Wp2, x_s);
        hipLaunchKernelGGL(gemm1_kernel, grid_g, dim3(256), 0, stream,
                           x_s, Wp1, bias1, offsets, tile_o, tile_m, h1);
        hipLaunchKernelGGL(gemm2_kernel, grid_g, dim3(256), 0, stream,
                           h1, Wp2, bias2, sorted_idx, offsets, tile_o, tile_m, out);
    } else if (ws_size >= need_half) {
        // sequenced single-Wp fallback (proven-available ws footprint)
        hipLaunchKernelGGL(pack_x_kernel, dim3(Bn), dim3(256), 0, stream,
                           x, sorted_idx, x_s);
        hipLaunchKernelGGL(pack_w_kernel, dim3(Hn / 256, En / 8, On), dim3(256), 0, stream,
                           W1, Wp1);
        hipLaunchKernelGGL(gemm1_kernel, grid_g, dim3(256), 0, stream,
                           x_s, Wp1, bias1, offsets, tile_o, tile_m, h1);
        hipLaunchKernelGGL(pack_w_kernel, dim3(Hn / 256, Hn / 8, On), dim3(256), 0, stream,
                           W2, Wp1);
        hipLaunchKernelGGL(gemm2_kernel, grid_g, dim3(256), 0, stream,
                           h1, Wp1, bias2, sorted_idx, offsets, tile_o, tile_m, out);
    }
}